// Round 5
// baseline (324.804 us; speedup 1.0000x reference)
//
#include <hip/hip_runtime.h>

#define N_NODES 50000
#define N_EDGES 800000
#define N_GRAPHS 512
#define DIM 128
#define N_PAD 50048

#define BW_LOG 9
#define BWID 512                                  // nodes per bucket
#define NB ((N_NODES + BWID - 1) / BWID)          // 98
#define CHUNK 4096                                // edges per phase-A block
#define NCHUNK ((N_EDGES + CHUNK - 1) / CHUNK)    // 196

// eighth-major H layout: H8[s][node][16 feats], slice = 1.6 MB -> L2-resident when
// pinned to one XCD via s = blockIdx & 7 (round-robin block->XCD mapping).
#define SLOFF(s) ((size_t)(s) * N_PAD * 16)

#define COLCAP 2688                               // staged cols per 128-node block

typedef unsigned int uint;
typedef unsigned short ushort;
typedef __attribute__((ext_vector_type(8))) short bf16x8;
typedef __attribute__((ext_vector_type(4))) float f32x4;

// bf16 helpers (RNE pack, cheap unpack)
__device__ __forceinline__ ushort f2bf(float f) {
    uint u = __float_as_uint(f);
    return (ushort)((u + 0x7fffu + ((u >> 16) & 1u)) >> 16);
}
__device__ __forceinline__ float bf2f(ushort h) { return __uint_as_float((uint)h << 16); }
__device__ __forceinline__ float bflo(uint p) { return __uint_as_float(p << 16); }
__device__ __forceinline__ float bfhi(uint p) { return __uint_as_float(p & 0xffff0000u); }

// ---------------- CSR build phase A: bucket histogram (+ independent wconv) -------

__global__ __launch_bounds__(256) void bhist_wconv_k(const int* __restrict__ dst,
                                                     int* __restrict__ bcnt_pad, int e,
                                                     const float* __restrict__ Wa,
                                                     const float* __restrict__ Wb,
                                                     const float* __restrict__ Wc,
                                                     ushort* __restrict__ Whi,
                                                     ushort* __restrict__ Wlo) {
    int t = threadIdx.x;
    if (blockIdx.x < NCHUNK) {
        __shared__ int h[NB];
        for (int i = t; i < NB; i += 256) h[i] = 0;
        __syncthreads();
        int base = blockIdx.x * CHUNK;
        for (int i = t; i < CHUNK; i += 256) {
            int idx = base + i;
            if (idx < e) atomicAdd(&h[dst[idx] >> BW_LOG], 1);
        }
        __syncthreads();
        for (int i = t; i < NB; i += 256)
            if (h[i]) atomicAdd(&bcnt_pad[i << 4], h[i]);
        return;
    }
    int i = (blockIdx.x - NCHUNK) * 256 + t;      // 3*16384
    int layer = i >> 14, r = i & 16383;
    const float* W = layer == 0 ? Wa : (layer == 1 ? Wb : Wc);
    int k = r >> 7, nn = r & 127;
    float w = W[r];
    ushort h = f2bf(w);
    size_t o = (size_t)layer * DIM * DIM + nn * 128 + k;
    Whi[o] = h;
    Wlo[o] = f2bf(w - bf2f(h));
}

// parallel 98-wide exclusive scan (one 128-thread block)
__global__ void bscan_k(const int* __restrict__ bcnt_pad, int* __restrict__ bbase,
                        int* __restrict__ bcur_pad) {
    __shared__ int v[128];
    int t = threadIdx.x;
    int x = (t < NB) ? bcnt_pad[t << 4] : 0;
    v[t] = x;
    __syncthreads();
    for (int o = 1; o < 128; o <<= 1) {
        int val = v[t];
        int add = (t >= o) ? v[t - o] : 0;
        __syncthreads();
        v[t] = val + add;
        __syncthreads();
    }
    if (t < NB) {
        int excl = (t == 0) ? 0 : v[t - 1];
        bbase[t] = excl;
        bcur_pad[t << 4] = excl;
    }
    if (t == NB - 1) bbase[NB] = v[t];
}

// ---------------- bscat overlapped with gemm1 ----------------
// Blocks < NCHUNK: scatter packed edge records into bucket-sorted stage.
// Blocks >= NCHUNK: gemm1 = bf16(X @ W1), split-precision A and W, RAW output
// (no dis fold - dis isn't ready yet), eighth-major store.

__global__ __launch_bounds__(256) void bscat_gemm1_k(const int* __restrict__ src,
                                                     const int* __restrict__ dst,
                                                     int* __restrict__ bcur_pad,
                                                     uint* __restrict__ stage, int e,
                                                     const float* __restrict__ X,
                                                     const ushort* __restrict__ Whi,
                                                     const ushort* __restrict__ Wlo,
                                                     ushort* __restrict__ H, int n) {
    __shared__ __align__(16) ushort smem[128 * 136];   // 34.8 KB, dual-use
    int t = threadIdx.x;

    if (blockIdx.x < NCHUNK) {
        int* h  = (int*)smem;
        int* bb = h + NB;
        int* lc = bb + NB;
        for (int i = t; i < NB; i += 256) h[i] = 0;
        __syncthreads();
        int base = blockIdx.x * CHUNK;
        for (int i = t; i < CHUNK; i += 256) {
            int idx = base + i;
            if (idx < e) atomicAdd(&h[dst[idx] >> BW_LOG], 1);
        }
        __syncthreads();
        for (int i = t; i < NB; i += 256) {
            int c = h[i];
            bb[i] = c ? atomicAdd(&bcur_pad[i << 4], c) : 0;
            lc[i] = 0;
        }
        __syncthreads();
        for (int i = t; i < CHUNK; i += 256) {
            int idx = base + i;
            if (idx < e) {
                int d = dst[idx];
                int b = d >> BW_LOG;
                int r = atomicAdd(&lc[b], 1);
                stage[bb[b] + r] = ((uint)src[idx] << BW_LOG) | (uint)(d & (BWID - 1));
            }
        }
        return;
    }

    // ---- gemm1 ----
    ushort* lds = smem;
    int gb = blockIdx.x - NCHUNK;
    auto stageW = [&](const ushort* Wsw) {
#pragma unroll
        for (int j = 0; j < 8; j++) {
            int idx8 = t + j * 256;
            int nn = idx8 >> 4;
            int k0 = (idx8 & 15) * 8;
            uint4 v = ((const uint4*)Wsw)[idx8];
            *(uint4*)&lds[nn * 136 + k0] = v;
        }
    };
    stageW(Whi);

    int w = t >> 6, l = t & 63;
    int quad = l >> 4, lr = l & 15;
    int arow = gb * 64 + w * 16 + lr;
    int srow = arow < n ? arow : n - 1;

    bf16x8 a[4], alo[4];
#pragma unroll
    for (int q = 0; q < 4; q++) {
        const float4* xp = (const float4*)(X + (size_t)srow * DIM + q * 32 + quad * 8);
        float4 v0 = xp[0], v1 = xp[1];
        float f[8] = {v0.x, v0.y, v0.z, v0.w, v1.x, v1.y, v1.z, v1.w};
        bf16x8 ah, al;
#pragma unroll
        for (int j = 0; j < 8; j++) {
            ushort hh = f2bf(f[j]);
            ah[j] = (short)hh;
            al[j] = (short)f2bf(f[j] - bf2f(hh));
        }
        a[q] = ah;
        alo[q] = al;
    }

    f32x4 acc[8];
#pragma unroll
    for (int c = 0; c < 8; c++) acc[c] = (f32x4){0.f, 0.f, 0.f, 0.f};

    __syncthreads();
#pragma unroll
    for (int q = 0; q < 4; q++) {
#pragma unroll
        for (int c = 0; c < 8; c++) {
            bf16x8 b = *(const bf16x8*)&lds[(c * 16 + lr) * 136 + q * 32 + quad * 8];
            acc[c] = __builtin_amdgcn_mfma_f32_16x16x32_bf16(a[q], b, acc[c], 0, 0, 0);
            acc[c] = __builtin_amdgcn_mfma_f32_16x16x32_bf16(alo[q], b, acc[c], 0, 0, 0);
        }
    }
    __syncthreads();
    stageW(Wlo);
    __syncthreads();
#pragma unroll
    for (int q = 0; q < 4; q++) {
#pragma unroll
        for (int c = 0; c < 8; c++) {
            bf16x8 b = *(const bf16x8*)&lds[(c * 16 + lr) * 136 + q * 32 + quad * 8];
            acc[c] = __builtin_amdgcn_mfma_f32_16x16x32_bf16(a[q], b, acc[c], 0, 0, 0);
        }
    }
    __syncthreads();
#pragma unroll
    for (int c = 0; c < 8; c++) {
#pragma unroll
        for (int r = 0; r < 4; r++) {
            int rl = w * 16 + quad * 4 + r;
            lds[rl * 136 + c * 16 + lr] = f2bf(acc[c][r]);
        }
    }
    __syncthreads();
#pragma unroll
    for (int j = 0; j < 4; j++) {
        int idx = t + j * 256;                   // 1024 slots = 64 rows x 16 uint4
        int rl = idx >> 4, sl = idx & 15;
        int grow = gb * 64 + rl;
        if (grow < n) {
            uint4 v = *(const uint4*)&lds[rl * 136 + sl * 8];
            *(uint4*)(H + SLOFF(sl >> 1) + (size_t)grow * 16 + (sl & 1) * 8) = v;
        }
    }
}

__global__ __launch_bounds__(256) void csr_k(const uint* __restrict__ stage,
                                             const int* __restrict__ bbase,
                                             int* __restrict__ row_ptr,
                                             float* __restrict__ dis,
                                             int* __restrict__ col) {
    __shared__ int hist[BWID];
    __shared__ int excl[BWID];
    __shared__ int ws[256];
    int b = blockIdx.x, t = threadIdx.x;
    int beg = bbase[b], end = bbase[b + 1];
    for (int i = t; i < BWID; i += 256) hist[i] = 0;
    __syncthreads();
    for (int i = beg + t; i < end; i += 256)
        atomicAdd(&hist[stage[i] & (BWID - 1)], 1);
    __syncthreads();
    int s = hist[2 * t] + hist[2 * t + 1];
    ws[t] = s;
    __syncthreads();
    for (int o = 1; o < 256; o <<= 1) {
        int v = ws[t];
        int add = (t >= o) ? ws[t - o] : 0;
        __syncthreads();
        ws[t] = v + add;
        __syncthreads();
    }
    int pre = (t == 0) ? 0 : ws[t - 1];
    excl[2 * t] = pre;
    excl[2 * t + 1] = pre + hist[2 * t];
    __syncthreads();
    int node0 = b * BWID;
    for (int i = t; i < BWID; i += 256) {
        int node = node0 + i;
        if (node < N_NODES) {
            row_ptr[node] = beg + excl[i];
            dis[node] = rsqrtf((float)(hist[i] + 1));   // +1 = self-loop
        } else if (node == N_NODES) {
            row_ptr[node] = beg + excl[i];
        }
    }
    __syncthreads();
    for (int i = t; i < BWID; i += 256) hist[i] = excl[i];
    __syncthreads();
    for (int i = beg + t; i < end; i += 256) {
        uint p = stage[i];
        int d9 = p & (BWID - 1);
        int r = atomicAdd(&hist[d9], 1);
        col[beg + r] = (int)(p >> BW_LOG);
    }
}

// ---------------- XCD-pinned slice aggregation ----------------
// Round-5 rationale: R4's FETCH (~83-100MB/pass) = 8-XCD compulsory replication of
// H (12.8MB) -> every gather is an L2 miss; 100MB/50us = 2TB/s = HBM random-line
// BW ceiling. Fix: eighth-major H + slice pinned to XCD via s = blockIdx & 7
// (round-robin block->XCD). Each XCD gathers only its own 1.6MB slice -> L2-
// resident. 128 nodes/block, 2 lanes/node x 16B. Cols (+edge-dis for layer 1)
// staged in LDS once per block.

template <bool EDGE_DIS>
__global__ __launch_bounds__(256) void agg8_k(const ushort* __restrict__ H,
                                              const int* __restrict__ row_ptr,
                                              const int* __restrict__ col,
                                              const float* __restrict__ dis,
                                              const float* __restrict__ bias,
                                              ushort* __restrict__ Out, int n) {
    __shared__ int cols_s[COLCAP];
    __shared__ float dis_s[COLCAP];
    int t = threadIdx.x;
    int s = blockIdx.x & 7;
    int nb = blockIdx.x >> 3;
    int first_n = nb * 128;
    int last_n = first_n + 128 < n ? first_n + 128 : n;
    int cbase = row_ptr[first_n];
    int ccnt = row_ptr[last_n] - cbase;
    if (ccnt > COLCAP) ccnt = COLCAP;
    for (int i = t; i < ccnt; i += 256) {
        int c = col[cbase + i];
        cols_s[i] = c;
        if (EDGE_DIS) dis_s[i] = dis[c];
    }
    __syncthreads();

    int node = first_n + (t >> 1);
    if (node >= n) return;
    int lane = t & 1;
    float dn = dis[node];
    int beg = row_ptr[node], end = row_ptr[node + 1];
    const ushort* Hl = H + SLOFF(s) + lane * 8;

    float a0, a1, a2, a3, a4, a5, a6, a7;
    {
        float ws = EDGE_DIS ? dn : 1.f;    // self-loop weight
        uint4 pw = *(const uint4*)(Hl + (size_t)node * 16);
        a0 = ws * bflo(pw.x); a1 = ws * bfhi(pw.x);
        a2 = ws * bflo(pw.y); a3 = ws * bfhi(pw.y);
        a4 = ws * bflo(pw.z); a5 = ws * bfhi(pw.z);
        a6 = ws * bflo(pw.w); a7 = ws * bfhi(pw.w);
    }
    for (int e = beg; e < end; e += 8) {
        int c_[8];
        float w_[8];
        uint4 p_[8];
#pragma unroll
        for (int j = 0; j < 8; j++) {
            int idx = e + j;
            float pv = (idx < end) ? 1.f : 0.f;
            idx = idx < end ? idx : beg;        // beg always valid when loop entered
            int li = idx - cbase;
            int c;
            float wv;
            if (li < ccnt) {
                c = cols_s[li];
                wv = EDGE_DIS ? dis_s[li] : 1.f;
            } else {
                c = col[idx];
                wv = EDGE_DIS ? dis[c] : 1.f;
            }
            c_[j] = c;
            w_[j] = pv * wv;
        }
#pragma unroll
        for (int j = 0; j < 8; j++) p_[j] = *(const uint4*)(Hl + (size_t)c_[j] * 16);
#pragma unroll
        for (int j = 0; j < 8; j++) {
            a0 += w_[j] * bflo(p_[j].x); a1 += w_[j] * bfhi(p_[j].x);
            a2 += w_[j] * bflo(p_[j].y); a3 += w_[j] * bfhi(p_[j].y);
            a4 += w_[j] * bflo(p_[j].z); a5 += w_[j] * bfhi(p_[j].z);
            a6 += w_[j] * bflo(p_[j].w); a7 += w_[j] * bfhi(p_[j].w);
        }
    }
    int d0 = s * 16 + lane * 8;
    a0 = fmaxf(a0 * dn + bias[d0 + 0], 0.f);
    a1 = fmaxf(a1 * dn + bias[d0 + 1], 0.f);
    a2 = fmaxf(a2 * dn + bias[d0 + 2], 0.f);
    a3 = fmaxf(a3 * dn + bias[d0 + 3], 0.f);
    a4 = fmaxf(a4 * dn + bias[d0 + 4], 0.f);
    a5 = fmaxf(a5 * dn + bias[d0 + 5], 0.f);
    a6 = fmaxf(a6 * dn + bias[d0 + 6], 0.f);
    a7 = fmaxf(a7 * dn + bias[d0 + 7], 0.f);
    uint4 o;
    o.x = (uint)f2bf(a0) | ((uint)f2bf(a1) << 16);
    o.y = (uint)f2bf(a2) | ((uint)f2bf(a3) << 16);
    o.z = (uint)f2bf(a4) | ((uint)f2bf(a5) << 16);
    o.w = (uint)f2bf(a6) | ((uint)f2bf(a7) << 16);
    *(uint4*)(Out + SLOFF(s) + (size_t)node * 16 + lane * 8) = o;
}

// layer-3 slice agg fused with global_add_pool: LDS run-reduction (16 feats/slice)
// over sorted batch ids, one global atomic per (run x slice-feature).
__global__ __launch_bounds__(256) void agg_pool8_k(const ushort* __restrict__ H,
                                                   const int* __restrict__ row_ptr,
                                                   const int* __restrict__ col,
                                                   const float* __restrict__ dis,
                                                   const float* __restrict__ bias,
                                                   const int* __restrict__ batch,
                                                   float* __restrict__ Out, int n) {
    __shared__ int cols_s[COLCAP];
    __shared__ float sacc[16];
    int t = threadIdx.x;
    int s = blockIdx.x & 7;
    int nb = blockIdx.x >> 3;
    int first_n = nb * 128;
    int last_n = first_n + 128 < n ? first_n + 128 : n;
    int cbase = row_ptr[first_n];
    int ccnt = row_ptr[last_n] - cbase;
    if (ccnt > COLCAP) ccnt = COLCAP;
    for (int i = t; i < ccnt; i += 256) cols_s[i] = col[cbase + i];
    __syncthreads();

    int node = first_n + (t >> 1);
    int lane = t & 1;
    float a0 = 0.f, a1 = 0.f, a2 = 0.f, a3 = 0.f, a4 = 0.f, a5 = 0.f, a6 = 0.f, a7 = 0.f;
    int g = -1;
    if (node < n) {
        float dn = dis[node];
        int beg = row_ptr[node], end = row_ptr[node + 1];
        const ushort* Hl = H + SLOFF(s) + lane * 8;
        uint4 pw = *(const uint4*)(Hl + (size_t)node * 16);
        a0 = bflo(pw.x); a1 = bfhi(pw.x);
        a2 = bflo(pw.y); a3 = bfhi(pw.y);
        a4 = bflo(pw.z); a5 = bfhi(pw.z);
        a6 = bflo(pw.w); a7 = bfhi(pw.w);
        for (int e = beg; e < end; e += 8) {
            int c_[8];
            float w_[8];
            uint4 p_[8];
#pragma unroll
            for (int j = 0; j < 8; j++) {
                int idx = e + j;
                w_[j] = (idx < end) ? 1.f : 0.f;
                idx = idx < end ? idx : beg;
                int li = idx - cbase;
                c_[j] = (li < ccnt) ? cols_s[li] : col[idx];
            }
#pragma unroll
            for (int j = 0; j < 8; j++) p_[j] = *(const uint4*)(Hl + (size_t)c_[j] * 16);
#pragma unroll
            for (int j = 0; j < 8; j++) {
                a0 += w_[j] * bflo(p_[j].x); a1 += w_[j] * bfhi(p_[j].x);
                a2 += w_[j] * bflo(p_[j].y); a3 += w_[j] * bfhi(p_[j].y);
                a4 += w_[j] * bflo(p_[j].z); a5 += w_[j] * bfhi(p_[j].z);
                a6 += w_[j] * bflo(p_[j].w); a7 += w_[j] * bfhi(p_[j].w);
            }
        }
        int d0 = s * 16 + lane * 8;
        a0 = fmaxf(a0 * dn + bias[d0 + 0], 0.f);
        a1 = fmaxf(a1 * dn + bias[d0 + 1], 0.f);
        a2 = fmaxf(a2 * dn + bias[d0 + 2], 0.f);
        a3 = fmaxf(a3 * dn + bias[d0 + 3], 0.f);
        a4 = fmaxf(a4 * dn + bias[d0 + 4], 0.f);
        a5 = fmaxf(a5 * dn + bias[d0 + 5], 0.f);
        a6 = fmaxf(a6 * dn + bias[d0 + 6], 0.f);
        a7 = fmaxf(a7 * dn + bias[d0 + 7], 0.f);
        g = batch[node];
    }
    int last = first_n + 127 < n ? first_n + 127 : n - 1;
    int g0 = batch[first_n], g1 = batch[last];
    int d0l = lane * 8;
    for (int gr = g0; gr <= g1; gr++) {
        if (t < 16) sacc[t] = 0.f;
        __syncthreads();
        if (g == gr) {
            atomicAdd(&sacc[d0l + 0], a0);
            atomicAdd(&sacc[d0l + 1], a1);
            atomicAdd(&sacc[d0l + 2], a2);
            atomicAdd(&sacc[d0l + 3], a3);
            atomicAdd(&sacc[d0l + 4], a4);
            atomicAdd(&sacc[d0l + 5], a5);
            atomicAdd(&sacc[d0l + 6], a6);
            atomicAdd(&sacc[d0l + 7], a7);
        }
        __syncthreads();
        if (t < 16) atomicAdd(&Out[gr * DIM + s * 16 + t], sacc[t]);
        __syncthreads();
    }
}

// ---------------- MFMA GEMM (layers 2,3): eighth-major in/out, dis-fold ----------

__global__ __launch_bounds__(256) void gemm8_k(const ushort* __restrict__ X,
                                               const ushort* __restrict__ Whi,
                                               const ushort* __restrict__ Wlo,
                                               const float* __restrict__ dis,
                                               ushort* __restrict__ H, int n) {
    __shared__ __align__(16) ushort lds[128 * 136];
    int t = threadIdx.x;
    auto stageW = [&](const ushort* Wsw) {
#pragma unroll
        for (int j = 0; j < 8; j++) {
            int idx8 = t + j * 256;
            int nn = idx8 >> 4;
            int k0 = (idx8 & 15) * 8;
            uint4 v = ((const uint4*)Wsw)[idx8];
            *(uint4*)&lds[nn * 136 + k0] = v;
        }
    };
    stageW(Whi);

    int w = t >> 6, l = t & 63;
    int quad = l >> 4, lr = l & 15;
    int arow = blockIdx.x * 64 + w * 16 + lr;
    int srow = arow < n ? arow : n - 1;

    bf16x8 a[4];
#pragma unroll
    for (int q = 0; q < 4; q++)
        a[q] = *(const bf16x8*)(X + SLOFF(2 * q + (quad >> 1)) + (size_t)srow * 16 +
                                (quad & 1) * 8);

    f32x4 acc[8];
#pragma unroll
    for (int c = 0; c < 8; c++) acc[c] = (f32x4){0.f, 0.f, 0.f, 0.f};

    __syncthreads();
#pragma unroll
    for (int q = 0; q < 4; q++) {
#pragma unroll
        for (int c = 0; c < 8; c++) {
            bf16x8 b = *(const bf16x8*)&lds[(c * 16 + lr) * 136 + q * 32 + quad * 8];
            acc[c] = __builtin_amdgcn_mfma_f32_16x16x32_bf16(a[q], b, acc[c], 0, 0, 0);
        }
    }
    __syncthreads();
    stageW(Wlo);
    __syncthreads();
#pragma unroll
    for (int q = 0; q < 4; q++) {
#pragma unroll
        for (int c = 0; c < 8; c++) {
            bf16x8 b = *(const bf16x8*)&lds[(c * 16 + lr) * 136 + q * 32 + quad * 8];
            acc[c] = __builtin_amdgcn_mfma_f32_16x16x32_bf16(a[q], b, acc[c], 0, 0, 0);
        }
    }

    // fold dis[row] for the next layer's plain-sum gather
    float dsc[4];
    int orow0 = blockIdx.x * 64 + w * 16 + quad * 4;
#pragma unroll
    for (int r = 0; r < 4; r++) {
        int rr = orow0 + r;
        if (rr > n - 1) rr = n - 1;
        dsc[r] = dis[rr];
    }
    __syncthreads();
#pragma unroll
    for (int c = 0; c < 8; c++) {
#pragma unroll
        for (int r = 0; r < 4; r++) {
            int rl = w * 16 + quad * 4 + r;
            lds[rl * 136 + c * 16 + lr] = f2bf(acc[c][r] * dsc[r]);
        }
    }
    __syncthreads();
#pragma unroll
    for (int j = 0; j < 4; j++) {
        int idx = t + j * 256;                   // 1024 slots = 64 rows x 16 uint4
        int rl = idx >> 4, sl = idx & 15;
        int grow = blockIdx.x * 64 + rl;
        if (grow < n) {
            uint4 v = *(const uint4*)&lds[rl * 136 + sl * 8];
            *(uint4*)(H + SLOFF(sl >> 1) + (size_t)grow * 16 + (sl & 1) * 8) = v;
        }
    }
}

// ---------------- launch ----------------

extern "C" void kernel_launch(void* const* d_in, const int* in_sizes, int n_in,
                              void* d_out, int out_size, void* d_ws, size_t ws_size,
                              hipStream_t stream) {
    const float* x  = (const float*)d_in[0];
    const float* W1 = (const float*)d_in[1];
    const float* b1 = (const float*)d_in[2];
    const float* W2 = (const float*)d_in[3];
    const float* b2 = (const float*)d_in[4];
    const float* W3 = (const float*)d_in[5];
    const float* b3 = (const float*)d_in[6];
    const int*   ei = (const int*)d_in[7];
    const int*   bv = (const int*)d_in[8];
    float* out = (float*)d_out;

    const int N = N_NODES, E = N_EDGES;

    char* p = (char*)d_ws;
    auto alloc = [&](size_t bytes) -> void* {
        void* r = (void*)p;
        p += (bytes + 255) & ~(size_t)255;
        return r;
    };
    int*    bcnt_pad = (int*)alloc((size_t)NB * 16 * 4);
    int*    bcur_pad = (int*)alloc((size_t)NB * 16 * 4);
    int*    bbase    = (int*)alloc((size_t)(NB + 1) * 4);
    int*    row_ptr  = (int*)alloc((size_t)(N + 1) * 4);
    float*  dis      = (float*)alloc((size_t)N * 4);
    uint*   stage    = (uint*)alloc((size_t)E * 4);
    int*    col      = (int*)alloc((size_t)E * 4);
    ushort* B1       = (ushort*)alloc((size_t)N_PAD * DIM * 2);
    ushort* B2       = (ushort*)alloc((size_t)N_PAD * DIM * 2);
    ushort* Whi      = (ushort*)alloc((size_t)3 * DIM * DIM * 2);
    ushort* Wlo      = (ushort*)alloc((size_t)3 * DIM * DIM * 2);

    const int* src = ei;
    const int* dst = ei + E;

    hipMemsetAsync(d_out, 0, (size_t)N_GRAPHS * DIM * sizeof(float), stream);
    hipMemsetAsync(bcnt_pad, 0, (size_t)NB * 16 * 4, stream);

    bhist_wconv_k<<<NCHUNK + 192, 256, 0, stream>>>(dst, bcnt_pad, E, W1, W2, W3, Whi, Wlo);
    bscan_k<<<1, 128, 0, stream>>>(bcnt_pad, bbase, bcur_pad);
    bscat_gemm1_k<<<NCHUNK + N_PAD / 64, 256, 0, stream>>>(src, dst, bcur_pad, stage, E,
                                                           x, Whi, Wlo, B1, N);
    csr_k<<<NB, 256, 0, stream>>>(stage, bbase, row_ptr, dis, col);

    int nbk = (N + 127) / 128;           // 391
    int agg_grid = nbk * 8;              // slice = blockIdx & 7 (XCD-pinned)
    int gemm_grid = N_PAD / 64;          // 782

    // layer 1: agg (edge-dis weights on raw H1) -> A1
    agg8_k<true><<<agg_grid, 256, 0, stream>>>(B1, row_ptr, col, dis, b1, B2, N);
    // layer 2: gemm (fold dis) -> Hfold2; agg (plain sum) -> A2
    gemm8_k<<<gemm_grid, 256, 0, stream>>>(B2, Whi + (size_t)DIM * DIM,
                                           Wlo + (size_t)DIM * DIM, dis, B1, N);
    agg8_k<false><<<agg_grid, 256, 0, stream>>>(B1, row_ptr, col, dis, b2, B2, N);
    // layer 3: gemm (fold dis) -> Hfold3; agg + pool
    gemm8_k<<<gemm_grid, 256, 0, stream>>>(B2, Whi + (size_t)2 * DIM * DIM,
                                           Wlo + (size_t)2 * DIM * DIM, dis, B1, N);
    agg_pool8_k<<<agg_grid, 256, 0, stream>>>(B1, row_ptr, col, dis, b3, bv, out, N);
}

// Round 6
// 264.568 us; speedup vs baseline: 1.2277x; 1.2277x over previous
//
#include <hip/hip_runtime.h>

#define N_NODES 50000
#define N_EDGES 800000
#define N_GRAPHS 512
#define DIM 128
#define N_PAD 50048

#define BW_LOG 9
#define BWID 512                                  // nodes per bucket
#define NB ((N_NODES + BWID - 1) / BWID)          // 98
#define CHUNK 4096                                // edges per phase-A block
#define NCHUNK ((N_EDGES + CHUNK - 1) / CHUNK)    // 196
#define BCAP 10240                                // bucket region capacity (mean 8192, +22 sigma)

typedef unsigned int uint;
typedef unsigned short ushort;
typedef __attribute__((ext_vector_type(8))) short bf16x8;
typedef __attribute__((ext_vector_type(4))) float f32x4;

// bf16 helpers (RNE pack, cheap unpack)
__device__ __forceinline__ ushort f2bf(float f) {
    uint u = __float_as_uint(f);
    return (ushort)((u + 0x7fffu + ((u >> 16) & 1u)) >> 16);
}
__device__ __forceinline__ float bf2f(ushort h) { return __uint_as_float((uint)h << 16); }
__device__ __forceinline__ float bflo(uint p) { return __uint_as_float(p << 16); }
__device__ __forceinline__ float bfhi(uint p) { return __uint_as_float(p & 0xffff0000u); }

// ---------------- dispatch 1: bucket-append scatter ∥ wconv (all 3 layers) --------
// R6: bhist+bscan eliminated. Records append into fixed bucket regions
// [b*BCAP, b*BCAP+cnt), cursors (bcur_pad, memset-0) hold per-bucket counts.
// wconv blocks convert W1/W2/W3 to split-precision n-major bf16 (independent).

__global__ __launch_bounds__(256) void bscat_wconv_k(const int* __restrict__ src,
                                                     const int* __restrict__ dst,
                                                     int* __restrict__ bcur_pad,
                                                     uint* __restrict__ stage, int e,
                                                     const float* __restrict__ Wa,
                                                     const float* __restrict__ Wb,
                                                     const float* __restrict__ Wc,
                                                     ushort* __restrict__ Whi,
                                                     ushort* __restrict__ Wlo) {
    int t = threadIdx.x;
    if (blockIdx.x < NCHUNK) {
        __shared__ int h[NB];
        __shared__ int bb[NB];
        __shared__ int lc[NB];
        for (int i = t; i < NB; i += 256) h[i] = 0;
        __syncthreads();
        int base = blockIdx.x * CHUNK;
        for (int i = t; i < CHUNK; i += 256) {
            int idx = base + i;
            if (idx < e) atomicAdd(&h[dst[idx] >> BW_LOG], 1);
        }
        __syncthreads();
        for (int i = t; i < NB; i += 256) {
            int c = h[i];
            bb[i] = c ? atomicAdd(&bcur_pad[i << 4], c) : 0;
            lc[i] = 0;
        }
        __syncthreads();
        for (int i = t; i < CHUNK; i += 256) {
            int idx = base + i;
            if (idx < e) {
                int d = dst[idx];
                int b = d >> BW_LOG;
                int r = atomicAdd(&lc[b], 1);
                int slot = bb[b] + r;
                if (slot < BCAP)
                    stage[(size_t)b * BCAP + slot] =
                        ((uint)src[idx] << BW_LOG) | (uint)(d & (BWID - 1));
            }
        }
        return;
    }
    int i = (blockIdx.x - NCHUNK) * 256 + t;      // 3*16384
    int layer = i >> 14, r = i & 16383;
    const float* W = layer == 0 ? Wa : (layer == 1 ? Wb : Wc);
    int k = r >> 7, nn = r & 127;
    float w = W[r];
    ushort h = f2bf(w);
    size_t o = (size_t)layer * DIM * DIM + nn * 128 + k;
    Whi[o] = h;
    Wlo[o] = f2bf(w - bf2f(h));
}

// ---------------- dispatch 2: csr (self-scan) ∥ gemm1 ----------------
// Blocks < NB: per-bucket CSR finalize. Prefix over the 98 bucket counts is
// computed in-block (reads final cursors). Blocks >= NB: gemm1 = bf16(X @ W1),
// split-precision A and W, raw row-major output (dis not folded; layer-1 agg
// applies dis[c] per edge — R2 showed that broadcast gather is ~free).

__global__ __launch_bounds__(256) void csr_gemm1_k(const uint* __restrict__ stage,
                                                   const int* __restrict__ bcur_pad,
                                                   int* __restrict__ row_ptr,
                                                   float* __restrict__ dis,
                                                   int* __restrict__ col,
                                                   const float* __restrict__ X,
                                                   const ushort* __restrict__ Whi,
                                                   const ushort* __restrict__ Wlo,
                                                   ushort* __restrict__ H, int n) {
    __shared__ __align__(16) ushort smem[128 * 136];   // 34.8 KB, dual-use
    int t = threadIdx.x;

    if (blockIdx.x < NB) {
        int* hist = (int*)smem;            // [BWID]
        int* excl = hist + BWID;           // [BWID]
        int* ws   = excl + BWID;           // [256]
        int* pv   = ws + 256;              // [128]
        int b = blockIdx.x;

        // 98-wide prefix of bucket counts (inclusive scan in pv)
        if (t < 128) pv[t] = (t < NB) ? bcur_pad[t << 4] : 0;
        __syncthreads();
        for (int o = 1; o < 128; o <<= 1) {
            int val = (t < 128) ? pv[t] : 0;
            int add = (t >= o && t < 128) ? pv[t - o] : 0;
            __syncthreads();
            if (t < 128) pv[t] = val + add;
            __syncthreads();
        }
        int cnt = bcur_pad[b << 4];
        if (cnt > BCAP) cnt = BCAP;
        int prefix = (b == 0) ? 0 : pv[b - 1];   // global CSR offset of this bucket
        int sbeg = b * BCAP, send = sbeg + cnt;

        for (int i = t; i < BWID; i += 256) hist[i] = 0;
        __syncthreads();
        for (int i = sbeg + t; i < send; i += 256)
            atomicAdd(&hist[stage[i] & (BWID - 1)], 1);
        __syncthreads();
        int s = hist[2 * t] + hist[2 * t + 1];
        ws[t] = s;
        __syncthreads();
        for (int o = 1; o < 256; o <<= 1) {
            int v = ws[t];
            int add = (t >= o) ? ws[t - o] : 0;
            __syncthreads();
            ws[t] = v + add;
            __syncthreads();
        }
        int pre = (t == 0) ? 0 : ws[t - 1];
        excl[2 * t] = pre;
        excl[2 * t + 1] = pre + hist[2 * t];
        __syncthreads();
        int node0 = b * BWID;
        for (int i = t; i < BWID; i += 256) {
            int node = node0 + i;
            if (node < N_NODES) {
                row_ptr[node] = prefix + excl[i];
                dis[node] = rsqrtf((float)(hist[i] + 1));   // +1 = self-loop
            } else if (node == N_NODES) {
                row_ptr[node] = prefix + excl[i];
            }
        }
        __syncthreads();
        for (int i = t; i < BWID; i += 256) hist[i] = excl[i];
        __syncthreads();
        for (int i = sbeg + t; i < send; i += 256) {
            uint p = stage[i];
            int d9 = p & (BWID - 1);
            int r = atomicAdd(&hist[d9], 1);
            col[prefix + r] = (int)(p >> BW_LOG);
        }
        return;
    }

    // ---- gemm1 ----
    ushort* lds = smem;
    int gb = blockIdx.x - NB;
    auto stageW = [&](const ushort* Wsw) {
#pragma unroll
        for (int j = 0; j < 8; j++) {
            int idx8 = t + j * 256;
            int nn = idx8 >> 4;
            int k0 = (idx8 & 15) * 8;
            uint4 v = ((const uint4*)Wsw)[idx8];
            *(uint4*)&lds[nn * 136 + k0] = v;
        }
    };
    stageW(Whi);

    int w = t >> 6, l = t & 63;
    int quad = l >> 4, lr = l & 15;
    int arow = gb * 64 + w * 16 + lr;
    int srow = arow < n ? arow : n - 1;

    bf16x8 a[4], alo[4];
#pragma unroll
    for (int q = 0; q < 4; q++) {
        const float4* xp = (const float4*)(X + (size_t)srow * DIM + q * 32 + quad * 8);
        float4 v0 = xp[0], v1 = xp[1];
        float f[8] = {v0.x, v0.y, v0.z, v0.w, v1.x, v1.y, v1.z, v1.w};
        bf16x8 ah, al;
#pragma unroll
        for (int j = 0; j < 8; j++) {
            ushort hh = f2bf(f[j]);
            ah[j] = (short)hh;
            al[j] = (short)f2bf(f[j] - bf2f(hh));
        }
        a[q] = ah;
        alo[q] = al;
    }

    f32x4 acc[8];
#pragma unroll
    for (int c = 0; c < 8; c++) acc[c] = (f32x4){0.f, 0.f, 0.f, 0.f};

    __syncthreads();
#pragma unroll
    for (int q = 0; q < 4; q++) {
#pragma unroll
        for (int c = 0; c < 8; c++) {
            bf16x8 b = *(const bf16x8*)&lds[(c * 16 + lr) * 136 + q * 32 + quad * 8];
            acc[c] = __builtin_amdgcn_mfma_f32_16x16x32_bf16(a[q], b, acc[c], 0, 0, 0);
            acc[c] = __builtin_amdgcn_mfma_f32_16x16x32_bf16(alo[q], b, acc[c], 0, 0, 0);
        }
    }
    __syncthreads();
    stageW(Wlo);
    __syncthreads();
#pragma unroll
    for (int q = 0; q < 4; q++) {
#pragma unroll
        for (int c = 0; c < 8; c++) {
            bf16x8 b = *(const bf16x8*)&lds[(c * 16 + lr) * 136 + q * 32 + quad * 8];
            acc[c] = __builtin_amdgcn_mfma_f32_16x16x32_bf16(a[q], b, acc[c], 0, 0, 0);
        }
    }
    __syncthreads();
#pragma unroll
    for (int c = 0; c < 8; c++) {
#pragma unroll
        for (int r = 0; r < 4; r++) {
            int rl = w * 16 + quad * 4 + r;
            lds[rl * 136 + c * 16 + lr] = f2bf(acc[c][r]);
        }
    }
    __syncthreads();
#pragma unroll
    for (int j = 0; j < 4; j++) {
        int idx = t + j * 256;                   // 1024 slots = 64 rows x 16 uint4
        int rl = idx >> 4, sl = idx & 15;
        int grow = gb * 64 + rl;
        if (grow < n) {
            uint4 v = *(const uint4*)&lds[rl * 136 + sl * 8];
            ((uint4*)(H + (size_t)grow * DIM))[sl] = v;
        }
    }
}

// ---------------- fused agg(layer i) + gemm(layer i+1) ----------------
// The pull-gather is pinned at ~50us/pass by a per-CU MSHR x fill-latency ceiling
// (R0-R5: ILP, request-count, L2/quarter/XCD residency all null; FETCH 83->20MB
// with no speedup). So overlap the GEMM under it: each block aggregates its 64
// rows (fp32, bias+ReLU), stages them in LDS, runs the split-W MFMA GEMM in-block.
// EDGE_DIS=true: Hin raw (layer1), weight = dis[c] per edge; false: Hin pre-folded.
// Epilogue folds dis[row] into Hout for the next layer's plain-sum gather.

template <bool EDGE_DIS>
__global__ __launch_bounds__(256) void fused_agg_gemm_k(
    const ushort* __restrict__ Hin, const int* __restrict__ row_ptr,
    const int* __restrict__ col, const float* __restrict__ dis,
    const float* __restrict__ bias, const ushort* __restrict__ Whi,
    const ushort* __restrict__ Wlo, ushort* __restrict__ Hout, int n) {
    __shared__ __align__(16) ushort wlds[128 * 136];   // 34.8 KB
    __shared__ __align__(16) ushort alds[64 * 136];    // 17.4 KB
    int t = threadIdx.x;

    // ---- phase A: aggregate 64 rows, 4 lanes/node x 32 feats ----
    int nl = t >> 2;                       // local row 0..63
    int lane = t & 3;                      // feats [lane*32, lane*32+32)
    int node = blockIdx.x * 64 + nl;
    int cnode = node < n ? node : n - 1;   // clamp (pad rows recompute n-1; harmless)
    float dn = dis[cnode];
    int beg = row_ptr[cnode], end = row_ptr[cnode + 1];

    float acc[32];
    {
        float ws = EDGE_DIS ? dn : 1.f;    // self-loop weight
        const ushort* rp = Hin + (size_t)cnode * DIM + lane * 32;
#pragma unroll
        for (int k = 0; k < 4; k++) {
            uint4 pv = *(const uint4*)(rp + k * 8);
            acc[k * 8 + 0] = ws * bflo(pv.x); acc[k * 8 + 1] = ws * bfhi(pv.x);
            acc[k * 8 + 2] = ws * bflo(pv.y); acc[k * 8 + 3] = ws * bfhi(pv.y);
            acc[k * 8 + 4] = ws * bflo(pv.z); acc[k * 8 + 5] = ws * bfhi(pv.z);
            acc[k * 8 + 6] = ws * bflo(pv.w); acc[k * 8 + 7] = ws * bfhi(pv.w);
        }
    }
    for (int e = beg; e < end; e += 4) {
        int ii[4];
        float wv[4];
#pragma unroll
        for (int j = 0; j < 4; j++) {
            int idx = e + j;
            wv[j] = (idx < end) ? 1.f : 0.f;
            ii[j] = idx < end ? idx : end - 1;
        }
        int c4[4];
#pragma unroll
        for (int j = 0; j < 4; j++) c4[j] = col[ii[j]];
        if (EDGE_DIS) {
#pragma unroll
            for (int j = 0; j < 4; j++) wv[j] *= dis[c4[j]];
        }
#pragma unroll
        for (int j = 0; j < 4; j++) {
            const ushort* rp = Hin + (size_t)c4[j] * DIM + lane * 32;
            float wj = wv[j];
#pragma unroll
            for (int k = 0; k < 4; k++) {
                uint4 pv = *(const uint4*)(rp + k * 8);
                acc[k * 8 + 0] += wj * bflo(pv.x); acc[k * 8 + 1] += wj * bfhi(pv.x);
                acc[k * 8 + 2] += wj * bflo(pv.y); acc[k * 8 + 3] += wj * bfhi(pv.y);
                acc[k * 8 + 4] += wj * bflo(pv.z); acc[k * 8 + 5] += wj * bfhi(pv.z);
                acc[k * 8 + 6] += wj * bflo(pv.w); acc[k * 8 + 7] += wj * bfhi(pv.w);
            }
        }
    }
    // bias + ReLU, pack to LDS as the GEMM A tile
#pragma unroll
    for (int k = 0; k < 4; k++) {
        float y0 = fmaxf(acc[k * 8 + 0] * dn + bias[lane * 32 + k * 8 + 0], 0.f);
        float y1 = fmaxf(acc[k * 8 + 1] * dn + bias[lane * 32 + k * 8 + 1], 0.f);
        float y2 = fmaxf(acc[k * 8 + 2] * dn + bias[lane * 32 + k * 8 + 2], 0.f);
        float y3 = fmaxf(acc[k * 8 + 3] * dn + bias[lane * 32 + k * 8 + 3], 0.f);
        float y4 = fmaxf(acc[k * 8 + 4] * dn + bias[lane * 32 + k * 8 + 4], 0.f);
        float y5 = fmaxf(acc[k * 8 + 5] * dn + bias[lane * 32 + k * 8 + 5], 0.f);
        float y6 = fmaxf(acc[k * 8 + 6] * dn + bias[lane * 32 + k * 8 + 6], 0.f);
        float y7 = fmaxf(acc[k * 8 + 7] * dn + bias[lane * 32 + k * 8 + 7], 0.f);
        uint4 o;
        o.x = (uint)f2bf(y0) | ((uint)f2bf(y1) << 16);
        o.y = (uint)f2bf(y2) | ((uint)f2bf(y3) << 16);
        o.z = (uint)f2bf(y4) | ((uint)f2bf(y5) << 16);
        o.w = (uint)f2bf(y6) | ((uint)f2bf(y7) << 16);
        *(uint4*)&alds[nl * 136 + lane * 32 + k * 8] = o;
    }

    // ---- phase B: gemm (64 x 128) @ (128 x 128), split-precision W ----
    auto stageW = [&](const ushort* Wsw) {
#pragma unroll
        for (int j = 0; j < 8; j++) {
            int idx8 = t + j * 256;
            int nn = idx8 >> 4;
            int k0 = (idx8 & 15) * 8;
            uint4 v = ((const uint4*)Wsw)[idx8];
            *(uint4*)&wlds[nn * 136 + k0] = v;
        }
    };
    stageW(Whi);
    __syncthreads();

    int w = t >> 6, l = t & 63;
    int quad = l >> 4, lr = l & 15;
    int arl = w * 16 + lr;                 // local A row
    bf16x8 a[4];
#pragma unroll
    for (int q = 0; q < 4; q++)
        a[q] = *(const bf16x8*)&alds[arl * 136 + q * 32 + quad * 8];

    f32x4 gacc[8];
#pragma unroll
    for (int c = 0; c < 8; c++) gacc[c] = (f32x4){0.f, 0.f, 0.f, 0.f};

#pragma unroll
    for (int q = 0; q < 4; q++) {
#pragma unroll
        for (int c = 0; c < 8; c++) {
            bf16x8 b = *(const bf16x8*)&wlds[(c * 16 + lr) * 136 + q * 32 + quad * 8];
            gacc[c] = __builtin_amdgcn_mfma_f32_16x16x32_bf16(a[q], b, gacc[c], 0, 0, 0);
        }
    }
    __syncthreads();
    stageW(Wlo);
    __syncthreads();
#pragma unroll
    for (int q = 0; q < 4; q++) {
#pragma unroll
        for (int c = 0; c < 8; c++) {
            bf16x8 b = *(const bf16x8*)&wlds[(c * 16 + lr) * 136 + q * 32 + quad * 8];
            gacc[c] = __builtin_amdgcn_mfma_f32_16x16x32_bf16(a[q], b, gacc[c], 0, 0, 0);
        }
    }

    // epilogue: fold dis[row] for the next layer (C/D row = w*16 + quad*4 + r)
    float dsc[4];
    int orow0 = blockIdx.x * 64 + w * 16 + quad * 4;
#pragma unroll
    for (int r = 0; r < 4; r++) {
        int rr = orow0 + r;
        if (rr > n - 1) rr = n - 1;
        dsc[r] = dis[rr];
    }
    __syncthreads();                       // all alds reads done (a-frags in regs)
#pragma unroll
    for (int c = 0; c < 8; c++) {
#pragma unroll
        for (int r = 0; r < 4; r++) {
            int rl = w * 16 + quad * 4 + r;
            alds[rl * 136 + c * 16 + lr] = f2bf(gacc[c][r] * dsc[r]);
        }
    }
    __syncthreads();
#pragma unroll
    for (int j = 0; j < 4; j++) {
        int idx = t + j * 256;             // 1024 slots = 64 rows x 16 uint4
        int rl = idx >> 4, sl = idx & 15;
        int grow = blockIdx.x * 64 + rl;
        if (grow < n) {
            uint4 v = *(const uint4*)&alds[rl * 136 + sl * 8];
            ((uint4*)(Hout + (size_t)grow * DIM))[sl] = v;
        }
    }
}

// ---------------- layer-3 agg fused with global_add_pool ----------------
// H pre-folded by fused2's epilogue -> plain-sum gather, 16 lanes/node, 8-edge
// unroll + predicated tail. LDS run-reduction over sorted batch ids, one global
// atomic per (run x feature).

__global__ __launch_bounds__(256) void agg_pool_k(const ushort* __restrict__ H,
                                                  const int* __restrict__ row_ptr,
                                                  const int* __restrict__ col,
                                                  const float* __restrict__ dis,
                                                  const float* __restrict__ bias,
                                                  const int* __restrict__ batch,
                                                  float* __restrict__ Out, int n) {
    __shared__ float sacc[DIM];
    int t = threadIdx.x;
    int node = blockIdx.x * 16 + (t >> 4);
    int lane = t & 15;
    int d0 = lane * 8;
    float a0 = 0.f, a1 = 0.f, a2 = 0.f, a3 = 0.f, a4 = 0.f, a5 = 0.f, a6 = 0.f, a7 = 0.f;
    int g = -1;
    if (node < n) {
        const ushort* Hl = H + lane * 8;
        float dn = dis[node];
        int beg = row_ptr[node], end = row_ptr[node + 1];
        uint4 pw = *(const uint4*)(Hl + (size_t)node * DIM);
        a0 = bflo(pw.x); a1 = bfhi(pw.x);
        a2 = bflo(pw.y); a3 = bfhi(pw.y);
        a4 = bflo(pw.z); a5 = bfhi(pw.z);
        a6 = bflo(pw.w); a7 = bfhi(pw.w);
        for (int e = beg; e < end; e += 8) {
            int c_[8];
            float w_[8];
            uint4 p_[8];
#pragma unroll
            for (int j = 0; j < 8; j++) {
                int idx = e + j;
                w_[j] = (idx < end) ? 1.f : 0.f;
                idx = idx < end ? idx : end - 1;
                c_[j] = col[idx];
            }
#pragma unroll
            for (int j = 0; j < 8; j++) p_[j] = *(const uint4*)(Hl + (size_t)c_[j] * DIM);
#pragma unroll
            for (int j = 0; j < 8; j++) {
                a0 += w_[j] * bflo(p_[j].x); a1 += w_[j] * bfhi(p_[j].x);
                a2 += w_[j] * bflo(p_[j].y); a3 += w_[j] * bfhi(p_[j].y);
                a4 += w_[j] * bflo(p_[j].z); a5 += w_[j] * bfhi(p_[j].z);
                a6 += w_[j] * bflo(p_[j].w); a7 += w_[j] * bfhi(p_[j].w);
            }
        }
        a0 = fmaxf(a0 * dn + bias[d0 + 0], 0.f);
        a1 = fmaxf(a1 * dn + bias[d0 + 1], 0.f);
        a2 = fmaxf(a2 * dn + bias[d0 + 2], 0.f);
        a3 = fmaxf(a3 * dn + bias[d0 + 3], 0.f);
        a4 = fmaxf(a4 * dn + bias[d0 + 4], 0.f);
        a5 = fmaxf(a5 * dn + bias[d0 + 5], 0.f);
        a6 = fmaxf(a6 * dn + bias[d0 + 6], 0.f);
        a7 = fmaxf(a7 * dn + bias[d0 + 7], 0.f);
        g = batch[node];
    }
    int first = blockIdx.x * 16;                       // always < n (grid = n/16)
    int last = first + 15 < n ? first + 15 : n - 1;
    int g0 = batch[first], g1 = batch[last];
    for (int gr = g0; gr <= g1; gr++) {
        if (t < DIM) sacc[t] = 0.f;
        __syncthreads();
        if (g == gr) {
            atomicAdd(&sacc[d0], a0);
            atomicAdd(&sacc[d0 + 1], a1);
            atomicAdd(&sacc[d0 + 2], a2);
            atomicAdd(&sacc[d0 + 3], a3);
            atomicAdd(&sacc[d0 + 4], a4);
            atomicAdd(&sacc[d0 + 5], a5);
            atomicAdd(&sacc[d0 + 6], a6);
            atomicAdd(&sacc[d0 + 7], a7);
        }
        __syncthreads();
        if (t < DIM) atomicAdd(&Out[gr * DIM + t], sacc[t]);
        __syncthreads();
    }
}

// ---------------- launch ----------------

extern "C" void kernel_launch(void* const* d_in, const int* in_sizes, int n_in,
                              void* d_out, int out_size, void* d_ws, size_t ws_size,
                              hipStream_t stream) {
    const float* x  = (const float*)d_in[0];
    const float* W1 = (const float*)d_in[1];
    const float* b1 = (const float*)d_in[2];
    const float* W2 = (const float*)d_in[3];
    const float* b2 = (const float*)d_in[4];
    const float* W3 = (const float*)d_in[5];
    const float* b3 = (const float*)d_in[6];
    const int*   ei = (const int*)d_in[7];
    const int*   bv = (const int*)d_in[8];
    float* out = (float*)d_out;

    const int N = N_NODES, E = N_EDGES;

    char* p = (char*)d_ws;
    auto alloc = [&](size_t bytes) -> void* {
        void* r = (void*)p;
        p += (bytes + 255) & ~(size_t)255;
        return r;
    };
    int*    bcur_pad = (int*)alloc((size_t)NB * 16 * 4);
    int*    row_ptr  = (int*)alloc((size_t)(N + 1) * 4);
    float*  dis      = (float*)alloc((size_t)N * 4);
    uint*   stage    = (uint*)alloc((size_t)NB * BCAP * 4);
    int*    col      = (int*)alloc((size_t)E * 4);
    ushort* B1       = (ushort*)alloc((size_t)N_PAD * DIM * 2);
    ushort* B2       = (ushort*)alloc((size_t)N_PAD * DIM * 2);
    ushort* Whi      = (ushort*)alloc((size_t)3 * DIM * DIM * 2);
    ushort* Wlo      = (ushort*)alloc((size_t)3 * DIM * DIM * 2);

    const int* src = ei;
    const int* dst = ei + E;

    hipMemsetAsync(d_out, 0, (size_t)N_GRAPHS * DIM * sizeof(float), stream);
    hipMemsetAsync(bcur_pad, 0, (size_t)NB * 16 * 4, stream);

    // d1: bucket-append scatter ∥ wconv(all 3 W)
    bscat_wconv_k<<<NCHUNK + 192, 256, 0, stream>>>(src, dst, bcur_pad, stage, E,
                                                    W1, W2, W3, Whi, Wlo);
    // d2: CSR finalize (self-scan) ∥ gemm1
    csr_gemm1_k<<<NB + N_PAD / 64, 256, 0, stream>>>(stage, bcur_pad, row_ptr, dis, col,
                                                     x, Whi, Wlo, B1, N);

    int gg = N_PAD / 64;   // 782
    // layer-1 agg (edge-dis weights on raw H1) + layer-2 gemm; H2 folded with dis
    fused_agg_gemm_k<true><<<gg, 256, 0, stream>>>(B1, row_ptr, col, dis, b1,
                                                   Whi + (size_t)DIM * DIM,
                                                   Wlo + (size_t)DIM * DIM, B2, N);
    // layer-2 agg (plain sum) + layer-3 gemm; H3 folded with dis
    fused_agg_gemm_k<false><<<gg, 256, 0, stream>>>(B2, row_ptr, col, dis, b2,
                                                    Whi + (size_t)2 * DIM * DIM,
                                                    Wlo + (size_t)2 * DIM * DIM, B1, N);
    // layer-3 agg + global_add_pool
    agg_pool_k<<<(N + 15) / 16, 256, 0, stream>>>(B1, row_ptr, col, dis, b3, bv, out, N);
}

// Round 7
// 262.856 us; speedup vs baseline: 1.2357x; 1.0065x over previous
//
#include <hip/hip_runtime.h>

#define N_NODES 50000
#define N_EDGES 800000
#define N_GRAPHS 512
#define DIM 128
#define N_PAD 50048

#define BW_LOG 9
#define BWID 512                                  // nodes per bucket
#define NB ((N_NODES + BWID - 1) / BWID)          // 98
#define CHUNK 4096                                // edges per phase-A block
#define NCHUNK ((N_EDGES + CHUNK - 1) / CHUNK)    // 196
#define BCAP 10240                                // bucket region capacity (mean 8192)
#define CSR_SPLIT 4                               // sub-blocks per bucket (d9-range split)
#define ZBLK 8                                    // d_out zero blocks

typedef unsigned int uint;
typedef unsigned short ushort;
typedef __attribute__((ext_vector_type(8))) short bf16x8;
typedef __attribute__((ext_vector_type(4))) float f32x4;

// bf16 helpers (RNE pack, cheap unpack)
__device__ __forceinline__ ushort f2bf(float f) {
    uint u = __float_as_uint(f);
    return (ushort)((u + 0x7fffu + ((u >> 16) & 1u)) >> 16);
}
__device__ __forceinline__ float bf2f(ushort h) { return __uint_as_float((uint)h << 16); }
__device__ __forceinline__ float bflo(uint p) { return __uint_as_float(p << 16); }
__device__ __forceinline__ float bfhi(uint p) { return __uint_as_float(p & 0xffff0000u); }

// ---------------- dispatch 1: bucket-append scatter ∥ wconv ∥ out-zero ----------
// Records append into fixed bucket regions [b*BCAP, b*BCAP+cnt), cursors
// (bcur_pad, memset-0) hold per-bucket counts. wconv blocks convert W1/2/3 to
// split-precision n-major bf16. Tail blocks zero d_out (replaces a memset dispatch).

__global__ __launch_bounds__(256) void bscat_wconv_k(const int* __restrict__ src,
                                                     const int* __restrict__ dst,
                                                     int* __restrict__ bcur_pad,
                                                     uint* __restrict__ stage, int e,
                                                     const float* __restrict__ Wa,
                                                     const float* __restrict__ Wb,
                                                     const float* __restrict__ Wc,
                                                     ushort* __restrict__ Whi,
                                                     ushort* __restrict__ Wlo,
                                                     float* __restrict__ out_zero) {
    int t = threadIdx.x;
    if (blockIdx.x < NCHUNK) {
        __shared__ int h[NB];
        __shared__ int bb[NB];
        __shared__ int lc[NB];
        for (int i = t; i < NB; i += 256) h[i] = 0;
        __syncthreads();
        int base = blockIdx.x * CHUNK;
        for (int i = t; i < CHUNK; i += 256) {
            int idx = base + i;
            if (idx < e) atomicAdd(&h[dst[idx] >> BW_LOG], 1);
        }
        __syncthreads();
        for (int i = t; i < NB; i += 256) {
            int c = h[i];
            bb[i] = c ? atomicAdd(&bcur_pad[i << 4], c) : 0;
            lc[i] = 0;
        }
        __syncthreads();
        for (int i = t; i < CHUNK; i += 256) {
            int idx = base + i;
            if (idx < e) {
                int d = dst[idx];
                int b = d >> BW_LOG;
                int r = atomicAdd(&lc[b], 1);
                int slot = bb[b] + r;
                if (slot < BCAP)
                    stage[(size_t)b * BCAP + slot] =
                        ((uint)src[idx] << BW_LOG) | (uint)(d & (BWID - 1));
            }
        }
        return;
    }
    if (blockIdx.x >= NCHUNK + 192) {
        // zero d_out: 512*128 floats = 16384 float4, ZBLK*256 threads x 8 each
        int zi = (blockIdx.x - (NCHUNK + 192)) * 256 + t;
        float4 z = {0.f, 0.f, 0.f, 0.f};
        float4* o = (float4*)out_zero;
#pragma unroll
        for (int j = 0; j < 8; j++) o[zi * 8 + j] = z;
        return;
    }
    int i = (blockIdx.x - NCHUNK) * 256 + t;      // 3*16384
    int layer = i >> 14, r = i & 16383;
    const float* W = layer == 0 ? Wa : (layer == 1 ? Wb : Wc);
    int k = r >> 7, nn = r & 127;
    float w = W[r];
    ushort h = f2bf(w);
    size_t o = (size_t)layer * DIM * DIM + nn * 128 + k;
    Whi[o] = h;
    Wlo[o] = f2bf(w - bf2f(h));
}

// ---------------- dispatch 2: csr (4 sub-blocks/bucket, self-scan) ∥ gemm1 --------
// R7: csr was 98 blocks (38% CU use) with long serial LDS-atomic passes — the
// dispatch straggler. Now CSR_SPLIT=4 sub-blocks per bucket: each redundantly
// histograms the full bucket (reads dominate anyway), but writes row_ptr/dis and
// scatters only its 128-node d9-range with a private cursor copy (no cross-block
// coordination). gemm1 blocks follow: bf16(X @ W1), split-precision A and W, raw
// row-major output (dis folded later; layer-1 agg applies dis[c] per edge).

__global__ __launch_bounds__(256) void csr_gemm1_k(const uint* __restrict__ stage,
                                                   const int* __restrict__ bcur_pad,
                                                   int* __restrict__ row_ptr,
                                                   float* __restrict__ dis,
                                                   int* __restrict__ col,
                                                   const float* __restrict__ X,
                                                   const ushort* __restrict__ Whi,
                                                   const ushort* __restrict__ Wlo,
                                                   ushort* __restrict__ H, int n) {
    __shared__ __align__(16) ushort smem[128 * 136];   // 34.8 KB, dual-use
    int t = threadIdx.x;

    if (blockIdx.x < NB * CSR_SPLIT) {
        int* hist = (int*)smem;            // [BWID]
        int* excl = hist + BWID;           // [BWID]
        int* ws   = excl + BWID;           // [256]
        int* pv   = ws + 256;              // [128]
        int b = blockIdx.x >> 2;
        int s = blockIdx.x & 3;

        // 98-wide prefix of bucket counts (inclusive scan in pv)
        if (t < 128) pv[t] = (t < NB) ? bcur_pad[t << 4] : 0;
        __syncthreads();
        for (int o = 1; o < 128; o <<= 1) {
            int val = (t < 128) ? pv[t] : 0;
            int add = (t >= o && t < 128) ? pv[t - o] : 0;
            __syncthreads();
            if (t < 128) pv[t] = val + add;
            __syncthreads();
        }
        int cnt = bcur_pad[b << 4];
        if (cnt > BCAP) cnt = BCAP;
        int prefix = (b == 0) ? 0 : pv[b - 1];   // global CSR offset of this bucket
        int sbeg = b * BCAP, send = sbeg + cnt;

        for (int i = t; i < BWID; i += 256) hist[i] = 0;
        __syncthreads();
        for (int i = sbeg + t; i < send; i += 256)
            atomicAdd(&hist[stage[i] & (BWID - 1)], 1);
        __syncthreads();
        int ssum = hist[2 * t] + hist[2 * t + 1];
        ws[t] = ssum;
        __syncthreads();
        for (int o = 1; o < 256; o <<= 1) {
            int v = ws[t];
            int add = (t >= o) ? ws[t - o] : 0;
            __syncthreads();
            ws[t] = v + add;
            __syncthreads();
        }
        int pre = (t == 0) ? 0 : ws[t - 1];
        excl[2 * t] = pre;
        excl[2 * t + 1] = pre + hist[2 * t];
        __syncthreads();
        int node0 = b * BWID;
        if (t < 128) {
            int i = s * 128 + t;           // this sub-block's node range
            int node = node0 + i;
            if (node < N_NODES) {
                row_ptr[node] = prefix + excl[i];
                dis[node] = rsqrtf((float)(hist[i] + 1));   // +1 = self-loop
            } else if (node == N_NODES) {
                row_ptr[node] = prefix + excl[i];
            }
        }
        __syncthreads();
        for (int i = t; i < BWID; i += 256) hist[i] = excl[i];
        __syncthreads();
        for (int i = sbeg + t; i < send; i += 256) {
            uint pck = stage[i];
            int d9 = pck & (BWID - 1);
            if ((d9 >> 7) == s) {          // own d9-range only (private cursors)
                int r = atomicAdd(&hist[d9], 1);
                col[prefix + r] = (int)(pck >> BW_LOG);
            }
        }
        return;
    }

    // ---- gemm1 ----
    ushort* lds = smem;
    int gb = blockIdx.x - NB * CSR_SPLIT;
    auto stageW = [&](const ushort* Wsw) {
#pragma unroll
        for (int j = 0; j < 8; j++) {
            int idx8 = t + j * 256;
            int nn = idx8 >> 4;
            int k0 = (idx8 & 15) * 8;
            uint4 v = ((const uint4*)Wsw)[idx8];
            *(uint4*)&lds[nn * 136 + k0] = v;
        }
    };
    stageW(Whi);

    int w = t >> 6, l = t & 63;
    int quad = l >> 4, lr = l & 15;
    int arow = gb * 64 + w * 16 + lr;
    int srow = arow < n ? arow : n - 1;

    bf16x8 a[4], alo[4];
#pragma unroll
    for (int q = 0; q < 4; q++) {
        const float4* xp = (const float4*)(X + (size_t)srow * DIM + q * 32 + quad * 8);
        float4 v0 = xp[0], v1 = xp[1];
        float f[8] = {v0.x, v0.y, v0.z, v0.w, v1.x, v1.y, v1.z, v1.w};
        bf16x8 ah, al;
#pragma unroll
        for (int j = 0; j < 8; j++) {
            ushort hh = f2bf(f[j]);
            ah[j] = (short)hh;
            al[j] = (short)f2bf(f[j] - bf2f(hh));
        }
        a[q] = ah;
        alo[q] = al;
    }

    f32x4 acc[8];
#pragma unroll
    for (int c = 0; c < 8; c++) acc[c] = (f32x4){0.f, 0.f, 0.f, 0.f};

    __syncthreads();
#pragma unroll
    for (int q = 0; q < 4; q++) {
#pragma unroll
        for (int c = 0; c < 8; c++) {
            bf16x8 b = *(const bf16x8*)&lds[(c * 16 + lr) * 136 + q * 32 + quad * 8];
            acc[c] = __builtin_amdgcn_mfma_f32_16x16x32_bf16(a[q], b, acc[c], 0, 0, 0);
            acc[c] = __builtin_amdgcn_mfma_f32_16x16x32_bf16(alo[q], b, acc[c], 0, 0, 0);
        }
    }
    __syncthreads();
    stageW(Wlo);
    __syncthreads();
#pragma unroll
    for (int q = 0; q < 4; q++) {
#pragma unroll
        for (int c = 0; c < 8; c++) {
            bf16x8 b = *(const bf16x8*)&lds[(c * 16 + lr) * 136 + q * 32 + quad * 8];
            acc[c] = __builtin_amdgcn_mfma_f32_16x16x32_bf16(a[q], b, acc[c], 0, 0, 0);
        }
    }
    __syncthreads();
#pragma unroll
    for (int c = 0; c < 8; c++) {
#pragma unroll
        for (int r = 0; r < 4; r++) {
            int rl = w * 16 + quad * 4 + r;
            lds[rl * 136 + c * 16 + lr] = f2bf(acc[c][r]);
        }
    }
    __syncthreads();
#pragma unroll
    for (int j = 0; j < 4; j++) {
        int idx = t + j * 256;                   // 1024 slots = 64 rows x 16 uint4
        int rl = idx >> 4, sl = idx & 15;
        int grow = gb * 64 + rl;
        if (grow < n) {
            uint4 v = *(const uint4*)&lds[rl * 136 + sl * 8];
            ((uint4*)(H + (size_t)grow * DIM))[sl] = v;
        }
    }
}

// ---------------- fused agg(layer i) + gemm(layer i+1) ----------------
// The pull-gather is pinned at ~50us/pass by a per-CU MSHR x fill-latency ceiling
// (R0-R5: ILP, request-count, L2/quarter/XCD residency all null; FETCH 83->20MB
// with no speedup). So overlap the GEMM under it: each block aggregates its 64
// rows (fp32, bias+ReLU), stages them in LDS, runs the split-W MFMA GEMM in-block.
// EDGE_DIS=true: Hin raw (layer1), weight = dis[c] per edge; false: Hin pre-folded.
// Epilogue folds dis[row] into Hout for the next layer's plain-sum gather.

template <bool EDGE_DIS>
__global__ __launch_bounds__(256) void fused_agg_gemm_k(
    const ushort* __restrict__ Hin, const int* __restrict__ row_ptr,
    const int* __restrict__ col, const float* __restrict__ dis,
    const float* __restrict__ bias, const ushort* __restrict__ Whi,
    const ushort* __restrict__ Wlo, ushort* __restrict__ Hout, int n) {
    __shared__ __align__(16) ushort wlds[128 * 136];   // 34.8 KB
    __shared__ __align__(16) ushort alds[64 * 136];    // 17.4 KB
    int t = threadIdx.x;

    // ---- phase A: aggregate 64 rows, 4 lanes/node x 32 feats ----
    int nl = t >> 2;                       // local row 0..63
    int lane = t & 3;                      // feats [lane*32, lane*32+32)
    int node = blockIdx.x * 64 + nl;
    int cnode = node < n ? node : n - 1;   // clamp (pad rows recompute n-1; harmless)
    float dn = dis[cnode];
    int beg = row_ptr[cnode], end = row_ptr[cnode + 1];

    float acc[32];
    {
        float ws = EDGE_DIS ? dn : 1.f;    // self-loop weight
        const ushort* rp = Hin + (size_t)cnode * DIM + lane * 32;
#pragma unroll
        for (int k = 0; k < 4; k++) {
            uint4 pv = *(const uint4*)(rp + k * 8);
            acc[k * 8 + 0] = ws * bflo(pv.x); acc[k * 8 + 1] = ws * bfhi(pv.x);
            acc[k * 8 + 2] = ws * bflo(pv.y); acc[k * 8 + 3] = ws * bfhi(pv.y);
            acc[k * 8 + 4] = ws * bflo(pv.z); acc[k * 8 + 5] = ws * bfhi(pv.z);
            acc[k * 8 + 6] = ws * bflo(pv.w); acc[k * 8 + 7] = ws * bfhi(pv.w);
        }
    }
    for (int e = beg; e < end; e += 4) {
        int ii[4];
        float wv[4];
#pragma unroll
        for (int j = 0; j < 4; j++) {
            int idx = e + j;
            wv[j] = (idx < end) ? 1.f : 0.f;
            ii[j] = idx < end ? idx : end - 1;
        }
        int c4[4];
#pragma unroll
        for (int j = 0; j < 4; j++) c4[j] = col[ii[j]];
        if (EDGE_DIS) {
#pragma unroll
            for (int j = 0; j < 4; j++) wv[j] *= dis[c4[j]];
        }
#pragma unroll
        for (int j = 0; j < 4; j++) {
            const ushort* rp = Hin + (size_t)c4[j] * DIM + lane * 32;
            float wj = wv[j];
#pragma unroll
            for (int k = 0; k < 4; k++) {
                uint4 pv = *(const uint4*)(rp + k * 8);
                acc[k * 8 + 0] += wj * bflo(pv.x); acc[k * 8 + 1] += wj * bfhi(pv.x);
                acc[k * 8 + 2] += wj * bflo(pv.y); acc[k * 8 + 3] += wj * bfhi(pv.y);
                acc[k * 8 + 4] += wj * bflo(pv.z); acc[k * 8 + 5] += wj * bfhi(pv.z);
                acc[k * 8 + 6] += wj * bflo(pv.w); acc[k * 8 + 7] += wj * bfhi(pv.w);
            }
        }
    }
    // bias + ReLU, pack to LDS as the GEMM A tile
#pragma unroll
    for (int k = 0; k < 4; k++) {
        float y0 = fmaxf(acc[k * 8 + 0] * dn + bias[lane * 32 + k * 8 + 0], 0.f);
        float y1 = fmaxf(acc[k * 8 + 1] * dn + bias[lane * 32 + k * 8 + 1], 0.f);
        float y2 = fmaxf(acc[k * 8 + 2] * dn + bias[lane * 32 + k * 8 + 2], 0.f);
        float y3 = fmaxf(acc[k * 8 + 3] * dn + bias[lane * 32 + k * 8 + 3], 0.f);
        float y4 = fmaxf(acc[k * 8 + 4] * dn + bias[lane * 32 + k * 8 + 4], 0.f);
        float y5 = fmaxf(acc[k * 8 + 5] * dn + bias[lane * 32 + k * 8 + 5], 0.f);
        float y6 = fmaxf(acc[k * 8 + 6] * dn + bias[lane * 32 + k * 8 + 6], 0.f);
        float y7 = fmaxf(acc[k * 8 + 7] * dn + bias[lane * 32 + k * 8 + 7], 0.f);
        uint4 o;
        o.x = (uint)f2bf(y0) | ((uint)f2bf(y1) << 16);
        o.y = (uint)f2bf(y2) | ((uint)f2bf(y3) << 16);
        o.z = (uint)f2bf(y4) | ((uint)f2bf(y5) << 16);
        o.w = (uint)f2bf(y6) | ((uint)f2bf(y7) << 16);
        *(uint4*)&alds[nl * 136 + lane * 32 + k * 8] = o;
    }

    // ---- phase B: gemm (64 x 128) @ (128 x 128), split-precision W ----
    auto stageW = [&](const ushort* Wsw) {
#pragma unroll
        for (int j = 0; j < 8; j++) {
            int idx8 = t + j * 256;
            int nn = idx8 >> 4;
            int k0 = (idx8 & 15) * 8;
            uint4 v = ((const uint4*)Wsw)[idx8];
            *(uint4*)&wlds[nn * 136 + k0] = v;
        }
    };
    stageW(Whi);
    __syncthreads();

    int w = t >> 6, l = t & 63;
    int quad = l >> 4, lr = l & 15;
    int arl = w * 16 + lr;                 // local A row
    bf16x8 a[4];
#pragma unroll
    for (int q = 0; q < 4; q++)
        a[q] = *(const bf16x8*)&alds[arl * 136 + q * 32 + quad * 8];

    f32x4 gacc[8];
#pragma unroll
    for (int c = 0; c < 8; c++) gacc[c] = (f32x4){0.f, 0.f, 0.f, 0.f};

#pragma unroll
    for (int q = 0; q < 4; q++) {
#pragma unroll
        for (int c = 0; c < 8; c++) {
            bf16x8 b = *(const bf16x8*)&wlds[(c * 16 + lr) * 136 + q * 32 + quad * 8];
            gacc[c] = __builtin_amdgcn_mfma_f32_16x16x32_bf16(a[q], b, gacc[c], 0, 0, 0);
        }
    }
    __syncthreads();
    stageW(Wlo);
    __syncthreads();
#pragma unroll
    for (int q = 0; q < 4; q++) {
#pragma unroll
        for (int c = 0; c < 8; c++) {
            bf16x8 b = *(const bf16x8*)&wlds[(c * 16 + lr) * 136 + q * 32 + quad * 8];
            gacc[c] = __builtin_amdgcn_mfma_f32_16x16x32_bf16(a[q], b, gacc[c], 0, 0, 0);
        }
    }

    // epilogue: fold dis[row] for the next layer (C/D row = w*16 + quad*4 + r)
    float dsc[4];
    int orow0 = blockIdx.x * 64 + w * 16 + quad * 4;
#pragma unroll
    for (int r = 0; r < 4; r++) {
        int rr = orow0 + r;
        if (rr > n - 1) rr = n - 1;
        dsc[r] = dis[rr];
    }
    __syncthreads();                       // all alds reads done (a-frags in regs)
#pragma unroll
    for (int c = 0; c < 8; c++) {
#pragma unroll
        for (int r = 0; r < 4; r++) {
            int rl = w * 16 + quad * 4 + r;
            alds[rl * 136 + c * 16 + lr] = f2bf(gacc[c][r] * dsc[r]);
        }
    }
    __syncthreads();
#pragma unroll
    for (int j = 0; j < 4; j++) {
        int idx = t + j * 256;             // 1024 slots = 64 rows x 16 uint4
        int rl = idx >> 4, sl = idx & 15;
        int grow = blockIdx.x * 64 + rl;
        if (grow < n) {
            uint4 v = *(const uint4*)&alds[rl * 136 + sl * 8];
            ((uint4*)(Hout + (size_t)grow * DIM))[sl] = v;
        }
    }
}

// ---------------- layer-3 agg fused with global_add_pool ----------------
// H pre-folded by fused2's epilogue -> plain-sum gather, 16 lanes/node, 8-edge
// unroll + predicated tail. LDS run-reduction over sorted batch ids, one global
// atomic per (run x feature).

__global__ __launch_bounds__(256) void agg_pool_k(const ushort* __restrict__ H,
                                                  const int* __restrict__ row_ptr,
                                                  const int* __restrict__ col,
                                                  const float* __restrict__ dis,
                                                  const float* __restrict__ bias,
                                                  const int* __restrict__ batch,
                                                  float* __restrict__ Out, int n) {
    __shared__ float sacc[DIM];
    int t = threadIdx.x;
    int node = blockIdx.x * 16 + (t >> 4);
    int lane = t & 15;
    int d0 = lane * 8;
    float a0 = 0.f, a1 = 0.f, a2 = 0.f, a3 = 0.f, a4 = 0.f, a5 = 0.f, a6 = 0.f, a7 = 0.f;
    int g = -1;
    if (node < n) {
        const ushort* Hl = H + lane * 8;
        float dn = dis[node];
        int beg = row_ptr[node], end = row_ptr[node + 1];
        uint4 pw = *(const uint4*)(Hl + (size_t)node * DIM);
        a0 = bflo(pw.x); a1 = bfhi(pw.x);
        a2 = bflo(pw.y); a3 = bfhi(pw.y);
        a4 = bflo(pw.z); a5 = bfhi(pw.z);
        a6 = bflo(pw.w); a7 = bfhi(pw.w);
        for (int e = beg; e < end; e += 8) {
            int c_[8];
            float w_[8];
            uint4 p_[8];
#pragma unroll
            for (int j = 0; j < 8; j++) {
                int idx = e + j;
                w_[j] = (idx < end) ? 1.f : 0.f;
                idx = idx < end ? idx : end - 1;
                c_[j] = col[idx];
            }
#pragma unroll
            for (int j = 0; j < 8; j++) p_[j] = *(const uint4*)(Hl + (size_t)c_[j] * DIM);
#pragma unroll
            for (int j = 0; j < 8; j++) {
                a0 += w_[j] * bflo(p_[j].x); a1 += w_[j] * bfhi(p_[j].x);
                a2 += w_[j] * bflo(p_[j].y); a3 += w_[j] * bfhi(p_[j].y);
                a4 += w_[j] * bflo(p_[j].z); a5 += w_[j] * bfhi(p_[j].z);
                a6 += w_[j] * bflo(p_[j].w); a7 += w_[j] * bfhi(p_[j].w);
            }
        }
        a0 = fmaxf(a0 * dn + bias[d0 + 0], 0.f);
        a1 = fmaxf(a1 * dn + bias[d0 + 1], 0.f);
        a2 = fmaxf(a2 * dn + bias[d0 + 2], 0.f);
        a3 = fmaxf(a3 * dn + bias[d0 + 3], 0.f);
        a4 = fmaxf(a4 * dn + bias[d0 + 4], 0.f);
        a5 = fmaxf(a5 * dn + bias[d0 + 5], 0.f);
        a6 = fmaxf(a6 * dn + bias[d0 + 6], 0.f);
        a7 = fmaxf(a7 * dn + bias[d0 + 7], 0.f);
        g = batch[node];
    }
    int first = blockIdx.x * 16;                       // always < n (grid = n/16)
    int last = first + 15 < n ? first + 15 : n - 1;
    int g0 = batch[first], g1 = batch[last];
    for (int gr = g0; gr <= g1; gr++) {
        if (t < DIM) sacc[t] = 0.f;
        __syncthreads();
        if (g == gr) {
            atomicAdd(&sacc[d0], a0);
            atomicAdd(&sacc[d0 + 1], a1);
            atomicAdd(&sacc[d0 + 2], a2);
            atomicAdd(&sacc[d0 + 3], a3);
            atomicAdd(&sacc[d0 + 4], a4);
            atomicAdd(&sacc[d0 + 5], a5);
            atomicAdd(&sacc[d0 + 6], a6);
            atomicAdd(&sacc[d0 + 7], a7);
        }
        __syncthreads();
        if (t < DIM) atomicAdd(&Out[gr * DIM + t], sacc[t]);
        __syncthreads();
    }
}

// ---------------- launch ----------------

extern "C" void kernel_launch(void* const* d_in, const int* in_sizes, int n_in,
                              void* d_out, int out_size, void* d_ws, size_t ws_size,
                              hipStream_t stream) {
    const float* x  = (const float*)d_in[0];
    const float* W1 = (const float*)d_in[1];
    const float* b1 = (const float*)d_in[2];
    const float* W2 = (const float*)d_in[3];
    const float* b2 = (const float*)d_in[4];
    const float* W3 = (const float*)d_in[5];
    const float* b3 = (const float*)d_in[6];
    const int*   ei = (const int*)d_in[7];
    const int*   bv = (const int*)d_in[8];
    float* out = (float*)d_out;

    const int N = N_NODES, E = N_EDGES;

    char* p = (char*)d_ws;
    auto alloc = [&](size_t bytes) -> void* {
        void* r = (void*)p;
        p += (bytes + 255) & ~(size_t)255;
        return r;
    };
    int*    bcur_pad = (int*)alloc((size_t)NB * 16 * 4);
    int*    row_ptr  = (int*)alloc((size_t)(N + 1) * 4);
    float*  dis      = (float*)alloc((size_t)N * 4);
    uint*   stage    = (uint*)alloc((size_t)NB * BCAP * 4);
    int*    col      = (int*)alloc((size_t)E * 4);
    ushort* B1       = (ushort*)alloc((size_t)N_PAD * DIM * 2);
    ushort* B2       = (ushort*)alloc((size_t)N_PAD * DIM * 2);
    ushort* Whi      = (ushort*)alloc((size_t)3 * DIM * DIM * 2);
    ushort* Wlo      = (ushort*)alloc((size_t)3 * DIM * DIM * 2);

    const int* src = ei;
    const int* dst = ei + E;

    hipMemsetAsync(bcur_pad, 0, (size_t)NB * 16 * 4, stream);

    // d1: bucket-append scatter ∥ wconv(all 3 W) ∥ d_out zero
    bscat_wconv_k<<<NCHUNK + 192 + ZBLK, 256, 0, stream>>>(src, dst, bcur_pad, stage, E,
                                                           W1, W2, W3, Whi, Wlo, out);
    // d2: CSR finalize (4 sub-blocks/bucket, self-scan) ∥ gemm1
    csr_gemm1_k<<<NB * CSR_SPLIT + N_PAD / 64, 256, 0, stream>>>(stage, bcur_pad,
                                                                 row_ptr, dis, col,
                                                                 x, Whi, Wlo, B1, N);

    int gg = N_PAD / 64;   // 782
    // layer-1 agg (edge-dis weights on raw H1) + layer-2 gemm; H2 folded with dis
    fused_agg_gemm_k<true><<<gg, 256, 0, stream>>>(B1, row_ptr, col, dis, b1,
                                                   Whi + (size_t)DIM * DIM,
                                                   Wlo + (size_t)DIM * DIM, B2, N);
    // layer-2 agg (plain sum) + layer-3 gemm; H3 folded with dis
    fused_agg_gemm_k<false><<<gg, 256, 0, stream>>>(B2, row_ptr, col, dis, b2,
                                                    Whi + (size_t)2 * DIM * DIM,
                                                    Wlo + (size_t)2 * DIM * DIM, B1, N);
    // layer-3 agg + global_add_pool
    agg_pool_k<<<(N + 15) / 16, 256, 0, stream>>>(B1, row_ptr, col, dis, b3, bv, out, N);
}